// Round 7
// baseline (222.123 us; speedup 1.0000x reference)
//
#include <hip/hip_runtime.h>
#include <math.h>

// Problem constants (from reference setup_inputs)
constexpr int B_  = 2;
constexpr int NS_ = 2048;
constexpr int NT_ = 32768;
constexpr int K_  = 32;
#define RADIUS_F 0.08f

constexpr int TPB = 512;                                 // 8 waves
constexpr int TGT_PER_WAVE = 8;
constexpr int TGT_PER_BLOCK = 8 * TGT_PER_WAVE;          // 64
constexpr int BLOCKS_PER_BATCH = NT_ / TGT_PER_BLOCK;    // 512
constexpr int NCHUNK = NS_ / 64;                         // 32

// Output layout: tuple concatenated flat, in return order (all float)
constexpr long long SZ_PATCH = (long long)B_ * NT_ * K_ * 3;
constexpr long long SZ_IDX   = (long long)B_ * NT_ * K_ * 2;
constexpr long long SZ_SIZE  = (long long)B_ * NT_;
constexpr long long SZ_RAD   = B_;
constexpr long long SZ_DIST  = (long long)B_ * NT_ * K_;
constexpr long long O_PATCH = 0;
constexpr long long O_IDX   = O_PATCH + SZ_PATCH;
constexpr long long O_SIZE  = O_IDX + SZ_IDX;
constexpr long long O_RAD   = O_SIZE + SZ_SIZE;
constexpr long long O_DIST  = O_RAD + SZ_RAD;
constexpr long long O_WD    = O_DIST + SZ_DIST;

// Compile-time bitonic take-min direction mask for stage (k,j)
constexpr unsigned long long tm_mask(int k, int j) {
    unsigned long long m = 0;
    for (int l = 0; l < 64; ++l)
        if (((l & k) == 0) == ((l & j) == 0)) m |= 1ull << l;
    return m;
}

#define INF_F __int_as_float(0x7f800000)

__device__ __forceinline__ float readlane_f(float v, int l) {
    return __int_as_float(__builtin_amdgcn_readlane(__float_as_int(v), l));
}
__device__ __forceinline__ float bperm_f(int addr, float v) {
    return __int_as_float(__builtin_amdgcn_ds_bpermute(addr, __float_as_int(v)));
}
// quad_perm DPP partner (xor1: 0xB1, xor2: 0x4E); ctrl must be a compile-time const
template<int CTRL>
__device__ __forceinline__ float dppq_f(float v) {
    return __int_as_float(__builtin_amdgcn_update_dpp(0, __float_as_int(v),
                                                      CTRL, 0xF, 0xF, true));
}
// r = mask ? a : b  (cndmask with SGPR-pair mask)
__device__ __forceinline__ float cndf(float a, float b, unsigned long long mask) {
    float r;
    asm("v_cndmask_b32 %0, %2, %1, %3" : "=v"(r) : "v"(a), "v"(b), "s"(mask));
    return r;
}
__device__ __forceinline__ int cndi(int a, int b, unsigned long long mask) {
    int r;
    asm("v_cndmask_b32 %0, %2, %1, %3" : "=v"(r) : "v"(a), "v"(b), "s"(mask));
    return r;
}
__device__ __forceinline__ int mbcnt64(unsigned long long m) {
    return __builtin_amdgcn_mbcnt_hi((unsigned)(m >> 32),
           __builtin_amdgcn_mbcnt_lo((unsigned)m, 0));
}
__device__ __forceinline__ float dist_f(float tx, float ty, float tz, float r0, float4 sp) {
    // match XLA: r0 - 2*dot + r1, mul/add chain, no fma contraction
    float dot = __fadd_rn(__fadd_rn(__fmul_rn(tx, sp.x), __fmul_rn(ty, sp.y)), __fmul_rn(tz, sp.z));
    return __fadd_rn(__fsub_rn(r0, __fmul_rn(2.0f, dot)), sp.w);
}

// compare-exchange with DPP partner (j=1,2); M = take-min direction mask variable
#define CEXD(LV, CTRL, M) { \
    float p_ = dppq_f<CTRL>(LV); \
    float mn_ = fminf(LV, p_); \
    float mx_ = fmaxf(LV, p_); \
    LV = cndf(mn_, mx_, M); \
}
// compare-exchange with bpermute partner (j>=4)
#define CEXB(LV, AJ, M) { \
    float p_ = bperm_f(AJ, LV); \
    float mn_ = fminf(LV, p_); \
    float mx_ = fmaxf(LV, p_); \
    LV = cndf(mn_, mx_, M); \
}

// full ascending bitonic sort of 64 values across the wave (21 stages)
#define SORT64(LV) \
    CEXD(LV, 0xB1, M_2_1) \
    CEXD(LV, 0x4E, M_4_2)  CEXD(LV, 0xB1, M_4_1) \
    CEXB(LV, a4, M_8_4)    CEXD(LV, 0x4E, M_8_2)  CEXD(LV, 0xB1, M_8_1) \
    CEXB(LV, a8, M_16_8)   CEXB(LV, a4, M_16_4)   CEXD(LV, 0x4E, M_16_2)  CEXD(LV, 0xB1, M_16_1) \
    CEXB(LV, a16, M_32_16) CEXB(LV, a8, M_32_8)   CEXB(LV, a4, M_32_4)    CEXD(LV, 0x4E, M_32_2) CEXD(LV, 0xB1, M_32_1) \
    CEXB(LV, a32, M_64_32) CEXB(LV, a16, M_64_16) CEXB(LV, a8, M_64_8)    CEXB(LV, a4, M_64_4)   CEXD(LV, 0x4E, M_64_2) CEXD(LV, 0xB1, M_64_1)

// ascending cleanup of a bitonic sequence (6 stages; same direction masks as k=64)
#define CLEAN64(LV) \
    CEXB(LV, a32, M_64_32) CEXB(LV, a16, M_64_16) CEXB(LV, a8, M_64_8) \
    CEXB(LV, a4, M_64_4)   CEXD(LV, 0x4E, M_64_2) CEXD(LV, 0xB1, M_64_1)

// flush buffer into sorted lv (keep low 64 of union), refresh threshold
#define FLUSH(LV, BUF, NBUF, T) { \
    unsigned long long vm_ = ((NBUF) >= 64) ? ~0ull : ((1ull << (NBUF)) - 1ull); \
    BUF = cndf(BUF, INF_F, vm_); \
    SORT64(BUF) \
    float mp_ = bperm_f(arev, BUF); \
    LV = fminf(LV, mp_); \
    CLEAN64(LV) \
    T = readlane_f(LV, 31); \
    NBUF = 0; \
}

// batched append of this chunk's qualifying candidates (d < T) into BUF
#define APPEND(D, LV, BUF, NBUF, T) { \
    unsigned long long m_ = __ballot((D) < (T)); \
    if (m_) { \
        int q_ = (int)__popcll(m_); \
        if ((NBUF) + q_ > 64) { \
            FLUSH(LV, BUF, NBUF, T) \
            m_ &= __ballot((D) < (T)); \
            q_ = (int)__popcll(m_); \
        } \
        if (m_) { \
            int mb_ = mbcnt64(m_); \
            int sel_ = cndi(mb_, q_ + lane - mb_, m_); \
            int pm_ = __builtin_amdgcn_ds_permute(((NBUF) + sel_) << 2, __float_as_int(D)); \
            int hi_ = (NBUF) + q_; \
            unsigned long long w1_ = (hi_ >= 64) ? ~0ull : ((1ull << hi_) - 1ull); \
            unsigned long long wm_ = w1_ & ~((1ull << (NBUF)) - 1ull); \
            BUF = cndf(__int_as_float(pm_), BUF, wm_); \
            NBUF = hi_; \
        } \
    } \
}

// record within-radius hits of D (rare), in index order
#define REC(D, RV, RI, NV, BASE) { \
    unsigned long long mr_ = __ballot(r2f >= (D)); \
    while (mr_) { \
        int sl_ = (int)__builtin_ctzll(mr_); mr_ &= mr_ - 1; \
        float v_ = readlane_f(D, sl_); \
        if (lane == (NV)) { RV = v_; RI = (BASE) + sl_; } \
        ++(NV); \
    } \
}

__device__ __forceinline__ void epilogue(
    float* __restrict__ out, const float* __restrict__ sden, const float4* ssp,
    int b, long long tb, int lane,
    float lv, float rv, int ri, int nv,
    float tx, float ty, float tz)
{
    const float invdd = 1.0f / (RADIUS_F + 1e-6f);
    int vflag = 0; int vidx = -1; float dsum = 0.f; int vcnt = 0;
    const long long sdb = (long long)b * NS_;
    const int nvc = (nv > 64) ? 64 : nv;
    for (int s = 0; s < nvc; ++s) {
        float vr = readlane_f(rv, s);
        int   ir = __builtin_amdgcn_readlane(ri, s);
        int rank = (int)__popcll(__ballot(lv < vr));
        for (int q = 0; q < s; ++q)                  // ties: earlier index first
            rank += (readlane_f(rv, q) == vr) ? 1 : 0;
        if (rank < K_) {
            dsum += sden[sdb + ir];
            ++vcnt;
            if (lane == rank) { vflag = 1; vidx = ir; }
        }
    }
    float px = 0.f, py = 0.f, pz = 0.f;
    if (vflag) { float4 spv = ssp[vidx]; px = spv.x; py = spv.y; pz = spv.z; }
    const float tsx = tx * invdd, tsy = ty * invdd, tsz = tz * invdd;
    if (lane < K_) {
        const long long pb = tb * K_ + lane;
        float3 p3;
        p3.x = (vflag ? px * invdd : 0.0f) - tsx;
        p3.y = (vflag ? py * invdd : 0.0f) - tsy;
        p3.z = (vflag ? pz * invdd : 0.0f) - tsz;
        *reinterpret_cast<float3*>(&out[O_PATCH + pb * 3]) = p3;
        float2 ix;
        ix.x = (float)b;
        ix.y = (float)vidx;                          // -1 when invalid
        *reinterpret_cast<float2*>(&out[O_IDX + pb * 2]) = ix;
        out[O_DIST + tb * K_ + lane] = sqrtf(fmaxf(lv, 1e-9f)) * invdd;
    }
    if (lane == 0) {
        out[O_SIZE + tb] = (float)vcnt;
        out[O_WD + tb]   = dsum / (float)(K_ - vcnt);
    }
}

__global__ __launch_bounds__(TPB, 8) void group_points_kernel(
    const float* __restrict__ src,
    const float* __restrict__ tgt,
    const float* __restrict__ sden,
    float* __restrict__ out)
{
    __shared__ float4 s_sp[NS_];                     // 32 KiB

    const int tid  = threadIdx.x;
    const int lane = tid & 63;
    const int wav  = tid >> 6;
    const int b    = blockIdx.x / BLOCKS_PER_BATCH;
    const int tile = blockIdx.x % BLOCKS_PER_BATCH;

    for (int j = tid; j < NS_; j += TPB) {
        const float* p = src + ((long long)b * NS_ + j) * 3;
        float x = p[0], y = p[1], z = p[2];
        float r1 = __fadd_rn(__fadd_rn(__fmul_rn(x, x), __fmul_rn(y, y)), __fmul_rn(z, z));
        s_sp[j] = make_float4(x, y, z, r1);
    }
    if (blockIdx.x == 0 && tid == 0) {
        out[O_RAD + 0] = RADIUS_F;
        out[O_RAD + 1] = RADIUS_F;
    }
    __syncthreads();

    const float r2f = __fmul_rn(RADIUS_F, RADIUS_F);
    // bpermute partner addresses
    const int a4   = (lane ^ 4)  << 2;
    const int a8   = (lane ^ 8)  << 2;
    const int a16  = (lane ^ 16) << 2;
    const int a32  = (lane ^ 32) << 2;
    const int arev = (63 - lane) << 2;
    // hoisted direction masks (SGPR pairs)
    const unsigned long long M_2_1   = tm_mask(2, 1);
    const unsigned long long M_4_2   = tm_mask(4, 2),  M_4_1  = tm_mask(4, 1);
    const unsigned long long M_8_4   = tm_mask(8, 4),  M_8_2  = tm_mask(8, 2),  M_8_1  = tm_mask(8, 1);
    const unsigned long long M_16_8  = tm_mask(16, 8), M_16_4 = tm_mask(16, 4), M_16_2 = tm_mask(16, 2), M_16_1 = tm_mask(16, 1);
    const unsigned long long M_32_16 = tm_mask(32, 16), M_32_8 = tm_mask(32, 8), M_32_4 = tm_mask(32, 4), M_32_2 = tm_mask(32, 2), M_32_1 = tm_mask(32, 1);
    const unsigned long long M_64_32 = tm_mask(64, 32), M_64_16 = tm_mask(64, 16), M_64_8 = tm_mask(64, 8), M_64_4 = tm_mask(64, 4), M_64_2 = tm_mask(64, 2), M_64_1 = tm_mask(64, 1);

    for (int gp = 0; gp < TGT_PER_WAVE / 4; ++gp) {
        const int t0 = tile * TGT_PER_BLOCK + wav * TGT_PER_WAVE + gp * 4;
        const long long tb0 = (long long)b * NT_ + t0;
        const float* tp = tgt + tb0 * 3;
        const float tx0 = tp[0],  ty0 = tp[1],  tz0 = tp[2];
        const float tx1 = tp[3],  ty1 = tp[4],  tz1 = tp[5];
        const float tx2 = tp[6],  ty2 = tp[7],  tz2 = tp[8];
        const float tx3 = tp[9],  ty3 = tp[10], tz3 = tp[11];
        const float r00 = __fadd_rn(__fadd_rn(__fmul_rn(tx0, tx0), __fmul_rn(ty0, ty0)), __fmul_rn(tz0, tz0));
        const float r01 = __fadd_rn(__fadd_rn(__fmul_rn(tx1, tx1), __fmul_rn(ty1, ty1)), __fmul_rn(tz1, tz1));
        const float r02 = __fadd_rn(__fadd_rn(__fmul_rn(tx2, tx2), __fmul_rn(ty2, ty2)), __fmul_rn(tz2, tz2));
        const float r03 = __fadd_rn(__fadd_rn(__fmul_rn(tx3, tx3), __fmul_rn(ty3, ty3)), __fmul_rn(tz3, tz3));

        // per-target state: sorted list lv (init +inf), buffer, count, threshold
        float lv0 = INF_F, lv1 = INF_F, lv2 = INF_F, lv3 = INF_F;
        float bf0 = 0.f, bf1 = 0.f, bf2 = 0.f, bf3 = 0.f;
        int   nb0 = 0, nb1 = 0, nb2 = 0, nb3 = 0;
        float T0 = INF_F, T1 = INF_F, T2 = INF_F, T3 = INF_F;
        float rv0 = 0.f, rv1 = 0.f, rv2 = 0.f, rv3 = 0.f;
        int   ri0 = 0,   ri1 = 0,   ri2 = 0,   ri3 = 0;
        int   nv0 = 0,   nv1 = 0,   nv2 = 0,   nv3 = 0;

        for (int c = 0; c < NCHUNK; ++c) {
            float4 sp = s_sp[(c << 6) + lane];
            float d0 = dist_f(tx0, ty0, tz0, r00, sp);
            float d1 = dist_f(tx1, ty1, tz1, r01, sp);
            float d2 = dist_f(tx2, ty2, tz2, r02, sp);
            float d3 = dist_f(tx3, ty3, tz3, r03, sp);

            // rare: any lane of any target within radius -> record hits in index order
            float g_ = fminf(fminf(d0, d1), fminf(d2, d3));
            if (__ballot(g_ <= r2f)) {
                const int base = c << 6;
                REC(d0, rv0, ri0, nv0, base)
                REC(d1, rv1, ri1, nv1, base)
                REC(d2, rv2, ri2, nv2, base)
                REC(d3, rv3, ri3, nv3, base)
            }

            APPEND(d0, lv0, bf0, nb0, T0)
            APPEND(d1, lv1, bf1, nb1, T1)
            APPEND(d2, lv2, bf2, nb2, T2)
            APPEND(d3, lv3, bf3, nb3, T3)
        }

        if (nb0) { FLUSH(lv0, bf0, nb0, T0) }
        if (nb1) { FLUSH(lv1, bf1, nb1, T1) }
        if (nb2) { FLUSH(lv2, bf2, nb2, T2) }
        if (nb3) { FLUSH(lv3, bf3, nb3, T3) }

        epilogue(out, sden, s_sp, b, tb0,     lane, lv0, rv0, ri0, nv0, tx0, ty0, tz0);
        epilogue(out, sden, s_sp, b, tb0 + 1, lane, lv1, rv1, ri1, nv1, tx1, ty1, tz1);
        epilogue(out, sden, s_sp, b, tb0 + 2, lane, lv2, rv2, ri2, nv2, tx2, ty2, tz2);
        epilogue(out, sden, s_sp, b, tb0 + 3, lane, lv3, rv3, ri3, nv3, tx3, ty3, tz3);
    }
}

extern "C" void kernel_launch(void* const* d_in, const int* in_sizes, int n_in,
                              void* d_out, int out_size, void* d_ws, size_t ws_size,
                              hipStream_t stream) {
    const float* src  = (const float*)d_in[0];   // (B,Ns,3)
    const float* tgt  = (const float*)d_in[1];   // (B,Nt,3)
    const float* sden = (const float*)d_in[2];   // (B,Ns,1)
    // d_in[3] = target_density: feeds only a dead value in the reference
    float* out = (float*)d_out;

    dim3 grid(B_ * BLOCKS_PER_BATCH);            // 1024 blocks
    group_points_kernel<<<grid, TPB, 0, stream>>>(src, tgt, sden, out);
}